// Round 2
// baseline (1214.341 us; speedup 1.0000x reference)
//
#include <hip/hip_runtime.h>

typedef unsigned short u16;
typedef unsigned int u32;
typedef __bf16 bf16x8 __attribute__((ext_vector_type(8)));
typedef float f32x4 __attribute__((ext_vector_type(4)));

#define B_ROWS 8192

// ---------- helpers ----------
__device__ __forceinline__ u16 f2bf(float f) {
    union { float f; u32 u; } v; v.f = f;
    u32 r = v.u + 0x7fffu + ((v.u >> 16) & 1u);   // RNE
    return (u16)(r >> 16);
}
__device__ __forceinline__ float gelu_erf(float x) {
    return 0.5f * x * (1.0f + erff(x * 0.70710678118654752f));
}
__device__ __forceinline__ float wave_reduce_sum(float v) {
    #pragma unroll
    for (int m = 32; m; m >>= 1) v += __shfl_xor(v, m, 64);
    return v;
}
__device__ __forceinline__ void async16(const void* g, void* l) {
    __builtin_amdgcn_global_load_lds((const __attribute__((address_space(1))) u32*)g,
                                     (__attribute__((address_space(3))) u32*)l, 16, 0, 0);
}

// ---------- absmean: sums[m] += sum(|w_m|), w fp32 2048x2048 ----------
__global__ void absmean_kernel(const float* __restrict__ w0, const float* __restrict__ w1,
                               const float* __restrict__ w2, const float* __restrict__ w3,
                               double* __restrict__ sums) {
    const float* w = (blockIdx.y == 0) ? w0 : (blockIdx.y == 1) ? w1 : (blockIdx.y == 2) ? w2 : w3;
    int t = blockIdx.x * 256 + threadIdx.x;  // vec4 index, grid.x=256 -> stride 65536
    float acc = 0.f;
    for (int i = t; i < 1048576; i += 65536) {
        float4 v = ((const float4*)w)[i];
        acc += fabsf(v.x) + fabsf(v.y) + fabsf(v.z) + fabsf(v.w);
    }
    acc = wave_reduce_sum(acc);
    __shared__ float red[4];
    int lane = threadIdx.x & 63, wv = threadIdx.x >> 6;
    if (lane == 0) red[wv] = acc;
    __syncthreads();
    if (threadIdx.x == 0) {
        atomicAdd(&sums[blockIdx.y], (double)(red[0] + red[1] + red[2] + red[3]));
    }
}

// ---------- ternary quantize: wq = round(clip(w/(s+1e-5),-1,1)) in {-1,0,1} bf16 ----------
// (scale s folded into GEMM epilogue -> exact ternary representation)
__global__ void quant_kernel(const float* __restrict__ w0, const float* __restrict__ w1,
                             const float* __restrict__ w2, const float* __restrict__ w3,
                             u16* __restrict__ wq, const double* __restrict__ sums) {
    int m = blockIdx.y;
    const float* w = (m == 0) ? w0 : (m == 1) ? w1 : (m == 2) ? w2 : w3;
    float s = (float)(sums[m] * (1.0 / 4194304.0));
    float den = s + 1e-5f;
    int i = blockIdx.x * 256 + threadIdx.x;  // vec4 idx, grid.x=4096
    float4 v = ((const float4*)w)[i];
    float q[4] = {v.x, v.y, v.z, v.w};
    ushort4 o;
    o.x = f2bf(rintf(fminf(fmaxf(q[0] / den, -1.f), 1.f)));
    o.y = f2bf(rintf(fminf(fmaxf(q[1] / den, -1.f), 1.f)));
    o.z = f2bf(rintf(fminf(fmaxf(q[2] / den, -1.f), 1.f)));
    o.w = f2bf(rintf(fminf(fmaxf(q[3] / den, -1.f), 1.f)));
    ((ushort4*)(wq + (size_t)m * 4194304))[i] = o;
}

// ---------- f32 -> bf16 bulk convert (mlp weights) ----------
__global__ void cvt_kernel(const float* __restrict__ in, u16* __restrict__ out) {
    int i = blockIdx.x * 256 + threadIdx.x;  // vec4 idx
    float4 v = ((const float4*)in)[i];
    ushort4 o = {f2bf(v.x), f2bf(v.y), f2bf(v.z), f2bf(v.w)};
    ((ushort4*)out)[i] = o;
}

// ---------- concat 5 fp32 inputs -> combined [8192,2048] bf16 ----------
__global__ void concat_kernel(const float* __restrict__ zb, const float* __restrict__ za,
                              const float* __restrict__ ze, const float* __restrict__ zm,
                              const float* __restrict__ zs, u16* __restrict__ out) {
    int row = blockIdx.x, t = threadIdx.x;
    int col = t * 8;
    const float* src; int scol, stride;
    if (col < 512)       { src = zb; scol = col;        stride = 512; }
    else if (col < 768)  { src = za; scol = col - 512;  stride = 256; }
    else if (col < 1024) { src = ze; scol = col - 768;  stride = 256; }
    else if (col < 1536) { src = zm; scol = col - 1024; stride = 512; }
    else                 { src = zs; scol = col - 1536; stride = 512; }
    const float4* s4 = (const float4*)(src + (size_t)row * stride + scol);
    float4 a = s4[0], b = s4[1];
    ushort4 p0 = {f2bf(a.x), f2bf(a.y), f2bf(a.z), f2bf(a.w)};
    ushort4 p1 = {f2bf(b.x), f2bf(b.y), f2bf(b.z), f2bf(b.w)};
    u16* o = out + (size_t)row * 2048 + col;
    *(ushort4*)o = p0;
    *(ushort4*)(o + 4) = p1;
}

// ---------- GEMM: C[M,N] = scale * (A[M,K] * W[N,K]^T) + bias, m97 structure ----------
// EPI 0: gelu(v) -> bf16 out
// EPI 1: v       -> f32 out
// EPI 2: sigmoid(1.2*gbuf)*v -> f32 out (out==gbuf ok: same-thread read-then-write)
template<int EPI>
__global__ __launch_bounds__(256) void gemm_bt(const u16* __restrict__ A, const u16* __restrict__ W,
                                               const float* __restrict__ bias, void* out,
                                               const float* gbuf,
                                               const double* sum_ptr, float inv_cnt,
                                               int M, int N, int K) {
    __shared__ __align__(16) u16 sA[128 * 32];
    __shared__ __align__(16) u16 sB[128 * 32];
    int t = threadIdx.x;
    int l = t & 63, w = t >> 6;
    int lr = l & 15, quad = l >> 4;
    int wm = (w & 1) * 64, wn = (w >> 1) * 64;
    int bn0 = blockIdx.x * 128, bm0 = blockIdx.y * 128;

    const u16* Ab = A + (size_t)bm0 * K;
    const u16* Wb = W + (size_t)bn0 * K;

    f32x4 acc[4][4] = {};

    for (int kt = 0; kt < K; kt += 32) {
        #pragma unroll
        for (int p = 0; p < 2; ++p) {
            int o = p * 256 + t;
            int row = o >> 2, kk = (o & 3) << 3;
            async16(Ab + (size_t)row * K + kt + kk, &sA[o * 8]);
            async16(Wb + (size_t)row * K + kt + kk, &sB[o * 8]);
        }
        __syncthreads();  // drains vmcnt (async LDS writes) + barrier
        bf16x8 af[4], bfr[4];
        #pragma unroll
        for (int i = 0; i < 4; ++i) {
            af[i]  = *(const bf16x8*)&sA[(wm + i * 16 + lr) * 32 + quad * 8];
            bfr[i] = *(const bf16x8*)&sB[(wn + i * 16 + lr) * 32 + quad * 8];
        }
        #pragma unroll
        for (int mt = 0; mt < 4; ++mt)
            #pragma unroll
            for (int nt = 0; nt < 4; ++nt)
                acc[mt][nt] = __builtin_amdgcn_mfma_f32_16x16x32_bf16(af[mt], bfr[nt], acc[mt][nt], 0, 0, 0);
        __syncthreads();
    }

    float scale = 1.f;
    if (sum_ptr) scale = (float)(*sum_ptr * (double)inv_cnt);

    // epilogue: C/D layout row=(l>>4)*4+reg, col=l&15 (m89-verified)
    #pragma unroll
    for (int nt = 0; nt < 4; ++nt) {
        int gcol = bn0 + wn + nt * 16 + lr;
        float bv = bias[gcol];
        #pragma unroll
        for (int mt = 0; mt < 4; ++mt) {
            #pragma unroll
            for (int i = 0; i < 4; ++i) {
                int grow = bm0 + wm + mt * 16 + quad * 4 + i;
                size_t idx = (size_t)grow * N + gcol;
                float v = acc[mt][nt][i] * scale + bv;
                if (EPI == 0) {
                    ((u16*)out)[idx] = f2bf(gelu_erf(v));
                } else if (EPI == 1) {
                    ((float*)out)[idx] = v;
                } else {
                    float g = gbuf[idx];
                    float sg = 1.f / (1.f + expf(-1.2f * g));
                    ((float*)out)[idx] = sg * v;
                }
            }
        }
    }
}

// ---------- layernorm over 2048 cols ----------
// MODE 0: x = x1;      write bf16 -> outb AND f32 back into x1 (LN1)
// MODE 1: x = x1 + x2; write f32 -> outf (LN2; outf may alias x2, same-thread RMW)
template<int MODE>
__global__ void ln_kernel(float* x1, const float* x2, u16* __restrict__ outb, float* outf,
                          const float* __restrict__ gam, const float* __restrict__ bet) {
    int row = blockIdx.x, t = threadIdx.x;
    float4* xv = (float4*)(x1 + (size_t)row * 2048);
    float4 a = xv[t], c = xv[t + 256];
    if (MODE == 1) {
        const float4* yv = (const float4*)(x2 + (size_t)row * 2048);
        float4 p = yv[t], q = yv[t + 256];
        a.x += p.x; a.y += p.y; a.z += p.z; a.w += p.w;
        c.x += q.x; c.y += q.y; c.z += q.z; c.w += q.w;
    }
    float s1 = a.x + a.y + a.z + a.w + c.x + c.y + c.z + c.w;
    float s2 = a.x * a.x + a.y * a.y + a.z * a.z + a.w * a.w
             + c.x * c.x + c.y * c.y + c.z * c.z + c.w * c.w;
    s1 = wave_reduce_sum(s1);
    s2 = wave_reduce_sum(s2);
    __shared__ float red[8];
    int lane = t & 63, wv = t >> 6;
    if (lane == 0) { red[wv] = s1; red[4 + wv] = s2; }
    __syncthreads();
    float S1 = red[0] + red[1] + red[2] + red[3];
    float S2 = red[4] + red[5] + red[6] + red[7];
    float mean = S1 * (1.f / 2048.f);
    float var = S2 * (1.f / 2048.f) - mean * mean;
    float r = rsqrtf(var + 1e-5f);

    int c0 = t * 4, c1 = 1024 + t * 4;
    float va[4] = {a.x, a.y, a.z, a.w}, vc[4] = {c.x, c.y, c.z, c.w};
    float oa[4], oc[4];
    #pragma unroll
    for (int j = 0; j < 4; ++j) {
        oa[j] = (va[j] - mean) * r * gam[c0 + j] + bet[c0 + j];
        oc[j] = (vc[j] - mean) * r * gam[c1 + j] + bet[c1 + j];
    }
    if (MODE == 0) {
        xv[t]       = make_float4(oa[0], oa[1], oa[2], oa[3]);
        xv[t + 256] = make_float4(oc[0], oc[1], oc[2], oc[3]);
        u16* ob = outb + (size_t)row * 2048;
        ushort4 pa = {f2bf(oa[0]), f2bf(oa[1]), f2bf(oa[2]), f2bf(oa[3])};
        ushort4 pc = {f2bf(oc[0]), f2bf(oc[1]), f2bf(oc[2]), f2bf(oc[3])};
        *(ushort4*)(ob + c0) = pa;
        *(ushort4*)(ob + c1) = pc;
    } else {
        float4* ov = (float4*)(outf + (size_t)row * 2048);
        ov[t]       = make_float4(oa[0], oa[1], oa[2], oa[3]);
        ov[t + 256] = make_float4(oc[0], oc[1], oc[2], oc[3]);
    }
}

// ---------- launch ----------
extern "C" void kernel_launch(void* const* d_in, const int* in_sizes, int n_in,
                              void* d_out, int out_size, void* d_ws, size_t ws_size,
                              hipStream_t stream) {
    const float* zb  = (const float*)d_in[0];
    const float* za  = (const float*)d_in[1];
    const float* ze  = (const float*)d_in[2];
    const float* zm  = (const float*)d_in[3];
    const float* zs  = (const float*)d_in[4];
    const float* gw1 = (const float*)d_in[5];  const float* gb1 = (const float*)d_in[6];
    const float* gw2 = (const float*)d_in[7];  const float* gb2 = (const float*)d_in[8];
    const float* tw1 = (const float*)d_in[9];  const float* tb1 = (const float*)d_in[10];
    const float* tw2 = (const float*)d_in[11]; const float* tb2 = (const float*)d_in[12];
    const float* mw1 = (const float*)d_in[13]; const float* mb1 = (const float*)d_in[14];
    const float* mw2 = (const float*)d_in[15]; const float* mb2 = (const float*)d_in[16];
    const float* l1g = (const float*)d_in[17]; const float* l1b = (const float*)d_in[18];
    const float* l2g = (const float*)d_in[19]; const float* l2b = (const float*)d_in[20];

    char* wsb = (char*)d_ws;
    // lifetime-aliased layout (bytes), total 192 MiB + 32 B:
    u16*   combined = (u16*)(wsb + 0);            // 33.5MB, dead after G2
    u16*   Hg       = (u16*)(wsb + 33554432);     // 33.5MB, dead after G3
    u16*   M1       = (u16*)(wsb + 0);            // 67MB, overlays combined+Hg (G5..G6)
    u16*   Ht       = (u16*)(wsb + 67108864);     // 33.5MB, dead after G4
    u16*   fusedb   = (u16*)(wsb + 67108864);     // 33.5MB, overlays Ht (LN1..G5)
    u16*   wq       = (u16*)(wsb + 100663296);    // 33.5MB (4x 2048x2048 bf16), dead after G4
    u16*   mwq      = (u16*)(wsb + 100663296);    // 33.5MB, overlays wq (written after G4)
    float* gbuf     = (float*)(wsb + 134217728);  // 67MB: g -> fused_pre -> fused f32 (live to LN2)
    double* sums    = (double*)(wsb + 201326592); // 32B
    float* mlp2     = (float*)d_out;              // 67MB: G6 output, then LN2 in-place

    const float inv = (float)(1.0 / 4194304.0);

    hipMemsetAsync(sums, 0, 4 * sizeof(double), stream);
    absmean_kernel<<<dim3(256, 4), 256, 0, stream>>>(gw1, tw1, gw2, tw2, sums);
    quant_kernel<<<dim3(4096, 4), 256, 0, stream>>>(gw1, tw1, gw2, tw2, wq, sums);
    concat_kernel<<<B_ROWS, 256, 0, stream>>>(zb, za, ze, zm, zs, combined);

    // G1: Hg = gelu(s0*(combined @ gw1q^T) + b1)
    gemm_bt<0><<<dim3(16, 64), 256, 0, stream>>>(combined, wq + 0,        gb1, Hg,   nullptr, &sums[0], inv, B_ROWS, 2048, 2048);
    // G2: Ht = gelu(s1*(combined @ tw1q^T) + b1)
    gemm_bt<0><<<dim3(16, 64), 256, 0, stream>>>(combined, wq + 4194304,  tb1, Ht,   nullptr, &sums[1], inv, B_ROWS, 2048, 2048);
    // G3: g = s2*(Hg @ gw2q^T) + b2  (f32)
    gemm_bt<1><<<dim3(16, 64), 256, 0, stream>>>(Hg,       wq + 8388608,  gb2, gbuf, nullptr, &sums[2], inv, B_ROWS, 2048, 2048);
    // G4: fused_pre = sigmoid(1.2*g) * (s3*(Ht @ tw2q^T) + b2)  (in-place over gbuf)
    gemm_bt<2><<<dim3(16, 64), 256, 0, stream>>>(Ht,       wq + 12582912, tb2, gbuf, gbuf,    &sums[3], inv, B_ROWS, 2048, 2048);

    // mlp weights -> bf16 (overlaying dead wq region)
    cvt_kernel<<<8192, 256, 0, stream>>>(mw1, mwq);
    cvt_kernel<<<8192, 256, 0, stream>>>(mw2, mwq + 8388608);

    // LN1: fused = LN(fused_pre) -> f32 in-place + bf16 copy
    ln_kernel<0><<<B_ROWS, 256, 0, stream>>>(gbuf, nullptr, fusedb, nullptr, l1g, l1b);
    // G5: M1 = gelu(fused @ mlp_w1^T + b) [8192 x 4096]
    gemm_bt<0><<<dim3(32, 64), 256, 0, stream>>>(fusedb, mwq,           mb1, M1,   nullptr, nullptr, 1.f, B_ROWS, 4096, 2048);
    // G6: mlp2 = M1 @ mlp_w2^T + b  (f32, K=4096) -> d_out as scratch
    gemm_bt<1><<<dim3(16, 64), 256, 0, stream>>>(M1,     mwq + 8388608, mb2, mlp2, nullptr, nullptr, 1.f, B_ROWS, 2048, 4096);
    // LN2: out = LN(fused + mlp2) -> f32 d_out (in-place over mlp2)
    ln_kernel<1><<<B_ROWS, 256, 0, stream>>>(gbuf, mlp2, nullptr, (float*)d_out, l2g, l2b);
}

// Round 5
// 1173.363 us; speedup vs baseline: 1.0349x; 1.0349x over previous
//
#include <hip/hip_runtime.h>

typedef unsigned short u16;
typedef unsigned int u32;
typedef __bf16 bf16x8 __attribute__((ext_vector_type(8)));
typedef float f32x4 __attribute__((ext_vector_type(4)));

#define B_ROWS 8192

// ---------- helpers ----------
__device__ __forceinline__ float bf2f(u16 h) {
    union { u32 u; float f; } v; v.u = ((u32)h) << 16; return v.f;
}
__device__ __forceinline__ u16 f2bf(float f) {
    union { float f; u32 u; } v; v.f = f;
    u32 r = v.u + 0x7fffu + ((v.u >> 16) & 1u);   // RNE
    return (u16)(r >> 16);
}
// tanh-approx gelu, overflow-safe (e=inf -> th=1)
__device__ __forceinline__ float gelu_fast(float x) {
    float u = x * (0.7978845608f + 0.0356774081f * x * x);
    float e = __expf(2.f * u);
    float th = 1.f - 2.f / (e + 1.f);
    return 0.5f * x * (1.f + th);
}
__device__ __forceinline__ float sigmoid12(float g) {
    return 1.f / (1.f + __expf(-1.2f * g));
}
__device__ __forceinline__ float wave_reduce_sum(float v) {
    #pragma unroll
    for (int m = 32; m; m >>= 1) v += __shfl_xor(v, m, 64);
    return v;
}
__device__ __forceinline__ void async16(const void* g, void* l) {
    __builtin_amdgcn_global_load_lds((const __attribute__((address_space(1))) u32*)g,
                                     (__attribute__((address_space(3))) u32*)l, 16, 0, 0);
}

// ---------- absmean stage 1: deterministic block partials (no atomics) ----------
// grid (64, 4): partials[m*64 + b] = sum(|w_m| over contiguous 64K-float slice)
__global__ void absmean1_kernel(const float* __restrict__ w0, const float* __restrict__ w1,
                                const float* __restrict__ w2, const float* __restrict__ w3,
                                float* __restrict__ partials) {
    const float* w = (blockIdx.y == 0) ? w0 : (blockIdx.y == 1) ? w1 : (blockIdx.y == 2) ? w2 : w3;
    int base = blockIdx.x * 16384;   // vec4 units
    float acc = 0.f;
    for (int j = threadIdx.x; j < 16384; j += 256) {
        float4 v = ((const float4*)w)[base + j];
        acc += fabsf(v.x) + fabsf(v.y) + fabsf(v.z) + fabsf(v.w);
    }
    acc = wave_reduce_sum(acc);
    __shared__ float red[4];
    int lane = threadIdx.x & 63, wv = threadIdx.x >> 6;
    if (lane == 0) red[wv] = acc;
    __syncthreads();
    if (threadIdx.x == 0)
        partials[blockIdx.y * 64 + blockIdx.x] = red[0] + red[1] + red[2] + red[3];
}

// ---------- absmean stage 2: fixed-order combine, grid (4), 64 threads ----------
__global__ void absmean2_kernel(const float* __restrict__ partials, double* __restrict__ sums) {
    float v = partials[blockIdx.x * 64 + threadIdx.x];
    v = wave_reduce_sum(v);
    if (threadIdx.x == 0) sums[blockIdx.x] = (double)v;
}

// ---------- prep: y<4 ternary-quantize {-1,0,1} bf16; y=4,5 cvt mlp weights ----------
__global__ void prep_kernel(const float* __restrict__ w0, const float* __restrict__ w1,
                            const float* __restrict__ w2, const float* __restrict__ w3,
                            const float* __restrict__ mw1, const float* __restrict__ mw2,
                            u16* __restrict__ wq, u16* __restrict__ mwq,
                            const double* __restrict__ sums) {
    int y = blockIdx.y;
    int i = blockIdx.x * 256 + threadIdx.x;   // vec4 index, grid.x = 4096
    if (y < 4) {
        const float* w = (y == 0) ? w0 : (y == 1) ? w1 : (y == 2) ? w2 : w3;
        float s = (float)(sums[y] * (1.0 / 4194304.0));
        float den = s + 1e-5f;
        float4 v = ((const float4*)w)[i];
        ushort4 o;
        o.x = f2bf(rintf(fminf(fmaxf(v.x / den, -1.f), 1.f)));
        o.y = f2bf(rintf(fminf(fmaxf(v.y / den, -1.f), 1.f)));
        o.z = f2bf(rintf(fminf(fmaxf(v.z / den, -1.f), 1.f)));
        o.w = f2bf(rintf(fminf(fmaxf(v.w / den, -1.f), 1.f)));
        ((ushort4*)(wq + (size_t)y * 4194304))[i] = o;
    } else {
        const float* src = (y == 4) ? mw1 : mw2;
        u16* dst = mwq + (y == 4 ? 0 : 8388608);
        #pragma unroll
        for (int r = 0; r < 2; ++r) {
            int j = i + r * 1048576;
            float4 v = ((const float4*)src)[j];
            ushort4 o = {f2bf(v.x), f2bf(v.y), f2bf(v.z), f2bf(v.w)};
            ((ushort4*)dst)[j] = o;
        }
    }
}

// ---------- concat 5 fp32 inputs -> combined [8192,2048] bf16 ----------
__global__ void concat_kernel(const float* __restrict__ zb, const float* __restrict__ za,
                              const float* __restrict__ ze, const float* __restrict__ zm,
                              const float* __restrict__ zs, u16* __restrict__ out) {
    int row = blockIdx.x, t = threadIdx.x;
    int col = t * 8;
    const float* src; int scol, stride;
    if (col < 512)       { src = zb; scol = col;        stride = 512; }
    else if (col < 768)  { src = za; scol = col - 512;  stride = 256; }
    else if (col < 1024) { src = ze; scol = col - 768;  stride = 256; }
    else if (col < 1536) { src = zm; scol = col - 1024; stride = 512; }
    else                 { src = zs; scol = col - 1536; stride = 512; }
    const float4* s4 = (const float4*)(src + (size_t)row * stride + scol);
    float4 a = s4[0], b = s4[1];
    ushort4 p0 = {f2bf(a.x), f2bf(a.y), f2bf(a.z), f2bf(a.w)};
    ushort4 p1 = {f2bf(b.x), f2bf(b.y), f2bf(b.z), f2bf(b.w)};
    u16* o = out + (size_t)row * 2048 + col;
    *(ushort4*)o = p0;
    *(ushort4*)(o + 4) = p1;
}

// ---------- GEMM: C = scale * (A[M,K(lda)] * W[N,K]^T) + bias ----------
// Swizzled LDS: slot (row, c) holds global chunk c ^ ((row>>1)&3)  (16B chunks).
// EPI 0: gelu(v) -> bf16 ; EPI 1: v -> f32 ; EPI 3: v -> bf16
// blockIdx.z==1 (dual mode): use A2/out2/bias1/sum1, W += wz.
template<int EPI>
__global__ __launch_bounds__(256) void gemm_bt(
        const u16* __restrict__ A, const u16* __restrict__ A2, int lda,
        const u16* __restrict__ W, int wz,
        const float* __restrict__ bias0, const float* __restrict__ bias1,
        void* out, void* out2,
        const double* sum0, const double* sum1,
        int N, int K, int ncut) {
    __shared__ __align__(16) u16 sA[128 * 32];
    __shared__ __align__(16) u16 sB[128 * 32];
    if (blockIdx.z) { A = A2; W += wz; out = out2; bias0 = bias1; sum0 = sum1; }

    int t = threadIdx.x;
    int l = t & 63, w = t >> 6;
    int lr = l & 15, quad = l >> 4;
    int sx = (lr >> 1) & 3;                 // read-side swizzle (lane-constant)
    int wm = (w & 1) * 64, wn = (w >> 1) * 64;
    int bn0 = blockIdx.x * 128, bm0 = blockIdx.y * 128;

    // staging addresses (swizzled global source chunk)
    int o0 = t, o1 = 256 + t;
    int r0 = o0 >> 2, r1 = o1 >> 2;
    int sw0 = (o0 ^ (r0 >> 1)) & 3, sw1 = (o1 ^ (r1 >> 1)) & 3;
    const u16* Ag0 = A + (size_t)(bm0 + r0) * lda + sw0 * 8;
    const u16* Ag1 = A + (size_t)(bm0 + r1) * lda + sw1 * 8;
    const u16* Wg0 = W + (size_t)(bn0 + r0) * K + sw0 * 8;
    const u16* Wg1 = W + (size_t)(bn0 + r1) * K + sw1 * 8;

    f32x4 acc[4][4] = {};

    for (int kt = 0; kt < K; kt += 32) {
        async16(Ag0 + kt, &sA[o0 * 8]);
        async16(Ag1 + kt, &sA[o1 * 8]);
        async16(Wg0 + kt, &sB[o0 * 8]);
        async16(Wg1 + kt, &sB[o1 * 8]);
        __syncthreads();  // drains vmcnt (async LDS writes) + barrier
        bf16x8 af[4], bfr[4];
        #pragma unroll
        for (int i = 0; i < 4; ++i) {
            af[i]  = *(const bf16x8*)&sA[(wm + i * 16 + lr) * 32 + ((quad ^ sx) * 8)];
            bfr[i] = *(const bf16x8*)&sB[(wn + i * 16 + lr) * 32 + ((quad ^ sx) * 8)];
        }
        #pragma unroll
        for (int mt = 0; mt < 4; ++mt)
            #pragma unroll
            for (int nt = 0; nt < 4; ++nt)
                acc[mt][nt] = __builtin_amdgcn_mfma_f32_16x16x32_bf16(af[mt], bfr[nt], acc[mt][nt], 0, 0, 0);
        __syncthreads();
    }

    float s0 = sum0 ? (float)(*sum0 * (1.0 / 4194304.0)) : 1.f;
    float s1 = sum1 ? (float)(*sum1 * (1.0 / 4194304.0)) : 1.f;

    // epilogue: C/D layout row=(l>>4)*4+reg, col=l&15 (m89-verified)
    #pragma unroll
    for (int nt = 0; nt < 4; ++nt) {
        int gcol = bn0 + wn + nt * 16 + lr;
        bool lo = gcol < ncut;
        float bv = lo ? bias0[gcol] : bias1[gcol - ncut];
        float sc = lo ? s0 : s1;
        #pragma unroll
        for (int mt = 0; mt < 4; ++mt) {
            #pragma unroll
            for (int i = 0; i < 4; ++i) {
                int grow = bm0 + wm + mt * 16 + quad * 4 + i;
                size_t idx = (size_t)grow * N + gcol;
                float v = acc[mt][nt][i] * sc + bv;
                if (EPI == 0)      ((u16*)out)[idx]   = f2bf(gelu_fast(v));
                else if (EPI == 1) ((float*)out)[idx] = v;
                else               ((u16*)out)[idx]   = f2bf(v);
            }
        }
    }
}

// ---------- LN1: f = sigmoid(1.2*g)*t ; LN(f) -> bf16 ----------
// outb may alias tt (same-thread read-before-write; rows disjoint across blocks)
__global__ void ln1_kernel(const u16* __restrict__ g, const u16* tt,
                           u16* outb,
                           const float* __restrict__ gam, const float* __restrict__ bet) {
    int row = blockIdx.x, t = threadIdx.x;
    int c0 = t * 8;
    uint4 gv = *(const uint4*)(g  + (size_t)row * 2048 + c0);
    uint4 tv = *(const uint4*)(tt + (size_t)row * 2048 + c0);
    u32 gw[4] = {gv.x, gv.y, gv.z, gv.w}, tw[4] = {tv.x, tv.y, tv.z, tv.w};
    float f[8];
    #pragma unroll
    for (int j = 0; j < 4; ++j) {
        f[2 * j]     = sigmoid12(bf2f((u16)(gw[j] & 0xffff))) * bf2f((u16)(tw[j] & 0xffff));
        f[2 * j + 1] = sigmoid12(bf2f((u16)(gw[j] >> 16)))    * bf2f((u16)(tw[j] >> 16));
    }
    float s1 = 0.f, s2 = 0.f;
    #pragma unroll
    for (int j = 0; j < 8; ++j) { s1 += f[j]; s2 += f[j] * f[j]; }
    s1 = wave_reduce_sum(s1); s2 = wave_reduce_sum(s2);
    __shared__ float red[8];
    int lane = t & 63, wv = t >> 6;
    if (lane == 0) { red[wv] = s1; red[4 + wv] = s2; }
    __syncthreads();
    float S1 = red[0] + red[1] + red[2] + red[3];
    float S2 = red[4] + red[5] + red[6] + red[7];
    float mean = S1 * (1.f / 2048.f);
    float var = S2 * (1.f / 2048.f) - mean * mean;
    float r = rsqrtf(var + 1e-5f);
    u16 ob[8];
    #pragma unroll
    for (int j = 0; j < 8; ++j)
        ob[j] = f2bf((f[j] - mean) * r * gam[c0 + j] + bet[c0 + j]);
    *(uint4*)(outb + (size_t)row * 2048 + c0) = *(uint4*)ob;
}

// ---------- LN2: x = fused(bf16) + mlp2(f32, in-place io) ; LN -> f32 io ----------
__global__ void ln2_kernel(const u16* __restrict__ fb, float* io,
                           const float* __restrict__ gam, const float* __restrict__ bet) {
    int row = blockIdx.x, t = threadIdx.x;
    int c0 = t * 8;
    uint4 fv = *(const uint4*)(fb + (size_t)row * 2048 + c0);
    u32 fw[4] = {fv.x, fv.y, fv.z, fv.w};
    float4* iov = (float4*)(io + (size_t)row * 2048 + c0);
    float4 m0 = iov[0], m1 = iov[1];
    float x[8] = {m0.x, m0.y, m0.z, m0.w, m1.x, m1.y, m1.z, m1.w};
    #pragma unroll
    for (int j = 0; j < 4; ++j) {
        x[2 * j]     += bf2f((u16)(fw[j] & 0xffff));
        x[2 * j + 1] += bf2f((u16)(fw[j] >> 16));
    }
    float s1 = 0.f, s2 = 0.f;
    #pragma unroll
    for (int j = 0; j < 8; ++j) { s1 += x[j]; s2 += x[j] * x[j]; }
    s1 = wave_reduce_sum(s1); s2 = wave_reduce_sum(s2);
    __shared__ float red[8];
    int lane = t & 63, wv = t >> 6;
    if (lane == 0) { red[wv] = s1; red[4 + wv] = s2; }
    __syncthreads();
    float S1 = red[0] + red[1] + red[2] + red[3];
    float S2 = red[4] + red[5] + red[6] + red[7];
    float mean = S1 * (1.f / 2048.f);
    float var = S2 * (1.f / 2048.f) - mean * mean;
    float r = rsqrtf(var + 1e-5f);
    float o[8];
    #pragma unroll
    for (int j = 0; j < 8; ++j)
        o[j] = (x[j] - mean) * r * gam[c0 + j] + bet[c0 + j];
    iov[0] = make_float4(o[0], o[1], o[2], o[3]);
    iov[1] = make_float4(o[4], o[5], o[6], o[7]);
}

// ---------- launch ----------
extern "C" void kernel_launch(void* const* d_in, const int* in_sizes, int n_in,
                              void* d_out, int out_size, void* d_ws, size_t ws_size,
                              hipStream_t stream) {
    const float* zb  = (const float*)d_in[0];
    const float* za  = (const float*)d_in[1];
    const float* ze  = (const float*)d_in[2];
    const float* zm  = (const float*)d_in[3];
    const float* zs  = (const float*)d_in[4];
    const float* gw1 = (const float*)d_in[5];  const float* gb1 = (const float*)d_in[6];
    const float* gw2 = (const float*)d_in[7];  const float* gb2 = (const float*)d_in[8];
    const float* tw1 = (const float*)d_in[9];  const float* tb1 = (const float*)d_in[10];
    const float* tw2 = (const float*)d_in[11]; const float* tb2 = (const float*)d_in[12];
    const float* mw1 = (const float*)d_in[13]; const float* mb1 = (const float*)d_in[14];
    const float* mw2 = (const float*)d_in[15]; const float* mb2 = (const float*)d_in[16];
    const float* l1g = (const float*)d_in[17]; const float* l1b = (const float*)d_in[18];
    const float* l2g = (const float*)d_in[19]; const float* l2b = (const float*)d_in[20];

    char* wsb = (char*)d_ws;
    // lifetime-aliased layout (MiB offsets):
    //   [0,32)    combined (dead after G12) -> gbuf (G34 z=0 out, dead after LN1)
    //   [32,64)   wq[0..3] (wq[0,1] dead after G12, wq[2,3] dead after G34)
    //   [64,96)   tbuf (G34 z=1 out) -> fusedb (LN1 in-place alias, live to LN2)
    //   [96,128)  mwq (mlp weights bf16, live to G6)
    //   [128,192) partials (1KiB, dead after absmean2) -> HgHt (dead after G34) -> M1
    //   [192]     sums (32 B)
    // AUDIT (race that broke r2-r4): tbuf must NOT overlap wq[2,3] [48,64) -- it
    // previously sat at [32,64) and G34's epilogue overwrote weights mid-K-loop.
    u16*   combined = (u16*)(wsb + 0);
    u16*   gbuf     = (u16*)(wsb + 0);
    u16*   wq       = (u16*)(wsb + 33554432);
    u16*   tbuf     = (u16*)(wsb + 67108864);
    u16*   fusedb   = (u16*)(wsb + 67108864);
    u16*   mwq      = (u16*)(wsb + 100663296);
    u16*   HgHt     = (u16*)(wsb + 134217728);
    u16*   M1       = (u16*)(wsb + 134217728);
    float* partials = (float*)(wsb + 134217728);
    double* sums    = (double*)(wsb + 201326592);
    float* mlp2     = (float*)d_out;              // G6 out, LN2 in-place

    // deterministic absmean (no atomics -> bit-identical across replays)
    absmean1_kernel<<<dim3(64, 4), 256, 0, stream>>>(gw1, tw1, gw2, tw2, partials);
    absmean2_kernel<<<4, 64, 0, stream>>>(partials, sums);
    prep_kernel<<<dim3(4096, 6), 256, 0, stream>>>(gw1, tw1, gw2, tw2, mw1, mw2, wq, mwq, sums);
    concat_kernel<<<B_ROWS, 256, 0, stream>>>(zb, za, ze, zm, zs, combined);

    // G12: HgHt = gelu(scale*(combined @ [gw1q;tw1q]^T) + [gb1;tb1]), N=4096
    gemm_bt<0><<<dim3(32, 64, 1), 256, 0, stream>>>(
        combined, nullptr, 2048, wq, 0, gb1, tb1, HgHt, nullptr,
        &sums[0], &sums[1], 4096, 2048, 2048);
    // G34 (dual-z): g = s2*(Hg @ gw2q^T)+gb2 ; t = s3*(Ht @ tw2q^T)+tb2  (bf16)
    gemm_bt<3><<<dim3(16, 64, 2), 256, 0, stream>>>(
        HgHt, HgHt + 2048, 4096, wq + 8388608, 4194304, gb2, tb2, gbuf, tbuf,
        &sums[2], &sums[3], 2048, 2048, 2048);
    // LN1: fusedb = LN(sigmoid(1.2*g)*t)  (in-place over tbuf, same-thread RMW)
    ln1_kernel<<<B_ROWS, 256, 0, stream>>>(gbuf, tbuf, fusedb, l1g, l1b);
    // G5: M1 = gelu(fusedb @ mlp_w1^T + mb1), N=4096
    gemm_bt<0><<<dim3(32, 64, 1), 256, 0, stream>>>(
        fusedb, nullptr, 2048, mwq, 0, mb1, mb1, M1, nullptr,
        nullptr, nullptr, 4096, 2048, 4096);
    // G6: mlp2 = M1 @ mlp_w2^T + mb2 (f32, K=4096) -> d_out
    gemm_bt<1><<<dim3(16, 64, 1), 256, 0, stream>>>(
        M1, nullptr, 4096, mwq + 8388608, 0, mb2, mb2, mlp2, nullptr,
        nullptr, nullptr, 2048, 4096, 2048);
    // LN2: d_out = LN(fusedb + mlp2), f32 in-place
    ln2_kernel<<<B_ROWS, 256, 0, stream>>>(fusedb, mlp2, l2g, l2b);
}